// Round 9
// baseline (14460.641 us; speedup 1.0000x reference)
//
#include <hip/hip_runtime.h>
#include <hip/hip_cooperative_groups.h>
#include <stdint.h>
#include <stddef.h>

namespace cg = cooperative_groups;

// ---------------------------------------------------------------------------
// Seq2Seq LSTM, MI355X persistent cooperative kernel.
// B=256, S=512, F=64, H=1024, T=64.  f32 I/O, bf16 MFMA internals.
//
// R21 -> R22: shave serial hops off the per-step chain (protocol unchanged).
// R21 facts: occupancy 12.4->24.8% bought only -10% => floor is the serial
// per-step communication chain (~25us/step), not intra-WG latency hiding.
// Chain model at achieved (DVFS-throttled) clock says detect-granularity
// and store-drain are the two shrinkable hops:
//  (a) poll loop: REMOVE s_sleep(8) -> pure RMW spin on go-lines. Every
//      waiter paid >=512cyc sleep before first check (1-2us at low clock).
//      15 pollers/line x ~1 RMW/600ns is far below LLC line serialization.
//  (b) h stores: back to R17's 256 x u64 agent atomics per WG (4 units/
//      thread, cst[4], tid<256) instead of R21's 512 x u32 -> halves the
//      write-through ops the pre-arrival __syncthreads must drain.
// Everything else byte-identical to R21 (512 thr / 8 waves / 2 per SIMD,
// wave=(mh,q) GEMM split, n-major ring, R17 go-line barrier, ring-8,
// encoder fence every 8 steps, decoder post-poll acquire).
//
// 256 WGs = 4 batch-groups (m, 64 rows) x 64 gate-slices (n, 16 hidden
// units -> 64 gate rows i/f/g/o). Weight slice persistent in LDS (139 KB,
// MFMA-B fragment order). h ring n-major: elem = n*4096 + row*16 + (k&15),
// per-WG 2KB private block.
// ---------------------------------------------------------------------------

typedef short s16x8 __attribute__((ext_vector_type(8)));
typedef float f32x4 __attribute__((ext_vector_type(4)));
typedef float f32x16 __attribute__((ext_vector_type(16)));

#define LDS_BYTES  156416
#define RED_OFF    139264   // 64x65 f32 reduction buffer
#define BIASG_OFF  155904   // 64 f32 gate bias
#define BIASFC_OFF 156160   // 64 f32 fc bias

// workspace layout (bytes)
#define WS_FLAGS 0          // counts: 4*576*4 = 9216 B (words 0..2303);
                            // go-lines: 16 x 128 B at word 2304
#define WS_HRING 12288      // 8 x 524288 B (ring of 256x1024 bf16 buffers)
#define WS_WFC   4206592    // 131072 B (64x1024 bf16)
// total: 4337664 B

#define HBUF_ELEMS 262144   // 256*1024 bf16 elements per ring buffer
#define GO_BASE    2304     // word offset of go-lines in flags[]

__device__ __forceinline__ unsigned short f2bf(float f) {
  union { unsigned int i; float f; } v;
  v.f = f;
  unsigned int i = v.i;
  return (unsigned short)((i + 0x7FFFu + ((i >> 16) & 1u)) >> 16);
}
__device__ __forceinline__ float sigm(float x) { return 1.f / (1.f + __expf(-x)); }
__device__ __forceinline__ float tanh_f(float x) {
  float e = __expf(2.f * x);
  return 1.f - 2.f / (e + 1.f);
}

// Stage this WG's weight slice (f32 global -> bf16 LDS, MFMA-B fragment
// order). 8 waves (f += 8).
__device__ __forceinline__ void load_wg(unsigned short* wl, float* biasg,
    const float* Wih, const float* Whh, const float* bih, const float* bhh,
    int n, int wave, int lane, int tid) {
  const int l31 = lane & 31;
  const int kh8 = (lane >> 5) << 3;
  for (int f = wave; f < 136; f += 8) {
    const int s  = f >> 1;
    const int t2 = f & 1;
    const int col = t2 * 32 + l31;
    const int k0  = s * 16 + kh8;
    const int r   = (col >> 4) * 1024 + n * 16 + (col & 15);
    const float* src = (s < 4) ? (Wih + (size_t)r * 64 + k0)
                               : (Whh + (size_t)r * 1024 + (k0 - 64));
    s16x8 w;
#pragma unroll
    for (int j = 0; j < 8; ++j) ((unsigned short*)&w)[j] = f2bf(src[j]);
    *(s16x8*)(wl + (size_t)f * 512 + lane * 8) = w;
  }
  if (tid < 64) {
    const int r = (tid >> 4) * 1024 + n * 16 + (tid & 15);
    biasg[tid] = bih[r] + bhh[r];
  }
}

// C/D layout (m74/m101-verified): col = lane&31,
// row = (r&3) + 8*(r>>2) + 4*(lane>>5), r in [0,16). mh = M-half (0/1).
__device__ __forceinline__ void red_write32(float* red, const f32x16 (&acc)[2],
                                            int lane, int mh, const float* bias) {
#pragma unroll
  for (int t2 = 0; t2 < 2; ++t2)
#pragma unroll
    for (int r = 0; r < 16; ++r) {
      const int row = mh * 32 + (r & 3) + ((r >> 2) << 3) + ((lane >> 5) << 2);
      const int col = t2 * 32 + (lane & 31);
      float v = acc[t2][r];
      if (bias) v += bias[col];
      red[row * 65 + col] = v;
    }
}
__device__ __forceinline__ void red_add32(float* red, const f32x16 (&acc)[2],
                                          int lane, int mh) {
#pragma unroll
  for (int t2 = 0; t2 < 2; ++t2)
#pragma unroll
    for (int r = 0; r < 16; ++r) {
      const int row = mh * 32 + (r & 3) + ((r >> 2) << 3) + ((lane >> 5) << 2);
      const int col = t2 * 32 + (lane & 31);
      atomicAdd(red + row * 65 + col, acc[t2][r]);
    }
}

__global__ void __launch_bounds__(512, 1) seq2seq_lstm(
    const float* __restrict__ xin,
    const float* __restrict__ Wih_e,
    const float* __restrict__ Whh_e,
    const float* __restrict__ bih_e,
    const float* __restrict__ bhh_e,
    const float* __restrict__ Wih_d,
    const float* __restrict__ Whh_d,
    const float* __restrict__ bih_d,
    const float* __restrict__ bhh_d,
    const float* __restrict__ Wfc,
    const float* __restrict__ bfc,
    float* __restrict__ out,
    unsigned short* __restrict__ hring,
    unsigned short* __restrict__ wfcb,
    unsigned int* __restrict__ flags) {
  extern __shared__ char smem[];
  unsigned short* wl = (unsigned short*)smem;
  float* red    = (float*)(smem + RED_OFF);
  float* biasg  = (float*)(smem + BIASG_OFF);
  float* biasfc = (float*)(smem + BIASFC_OFF);

  cg::grid_group grid = cg::this_grid();

  const int tid  = threadIdx.x;
  const int wave = tid >> 6;   // 0..7
  const int lane = tid & 63;
  const int wg   = blockIdx.x;
  const int m    = wg & 3;     // batch-group (XCD-locality swizzle)
  const int n    = wg >> 2;    // gate-slice
  const int bm   = m << 6;
  const int l31  = lane & 31;
  const int kh8  = (lane >> 5) << 3;
  const int mh   = wave & 1;   // M-half (rows mh*32..mh*32+31)
  const int q    = wave >> 1;  // K-quarter
  const int ks0  = q * 17;     // gates: this wave's k-step base (of 68)
  const int mrow = bm + mh * 32 + l31; // this lane's A row
  // activation mapping (tid < 256): row ar = tid>>2, units auu..auu+3
  const int ar   = tid >> 2;
  const int auu  = (tid & 3) << 2;

  load_wg(wl, biasg, Wih_e, Whh_e, bih_e, bhh_e, n, wave, lane, tid);

  // In-kernel init: zero ring buffer 7 (h_{-1}, this WG's n-major slice);
  // zero flag entries + go-lines; convert W_fc slice. grid.sync publishes.
  {
    if (tid < 256) {
      unsigned short* hinit = hring + (size_t)7 * HBUF_ELEMS;
      const size_t hq = ((size_t)n * 4096 + (size_t)(bm + ar) * 16 + auu) >> 2;
      __hip_atomic_store((unsigned long long*)hinit + hq, 0ull,
                         __ATOMIC_RELAXED, __HIP_MEMORY_SCOPE_AGENT);
      wfcb[wg * 256 + tid] = f2bf(Wfc[wg * 256 + tid]);
    }
    if (tid < 9)
      __hip_atomic_store(flags + wg * 9 + tid, 0u,
                         __ATOMIC_RELAXED, __HIP_MEMORY_SCOPE_AGENT);
    if (wg == 0 && tid < 16)
      __hip_atomic_store(flags + GO_BASE + tid * 32, 0u,
                         __ATOMIC_RELAXED, __HIP_MEMORY_SCOPE_AGENT);
  }
  __syncthreads();
  grid.sync(); // one-time full-coherence publish of init state

  float cst[4] = {0.f, 0.f, 0.f, 0.f};

  for (int gs = 0; gs < 576; ++gs) {
    const bool dec = (gs >= 512);
    const int t = gs - 512;

    // ---- amortized acquire fence: every 8 steps, before any h read ----
    if ((gs & 7) == 0 && gs != 0) {
      if (tid == 0) __builtin_amdgcn_fence(__ATOMIC_ACQUIRE, "agent");
      __syncthreads();
    }

    if (gs == 512) {
      __syncthreads();
      load_wg(wl, biasg, Wih_d, Whh_d, bih_d, bhh_d, n, wave, lane, tid);
      if (tid < 64) biasfc[tid] = bfc[tid];
      __syncthreads();
    }
    const unsigned short* hb = hring + (size_t)((gs + 7) & 7) * HBUF_ELEMS; // h_{gs-1}
    unsigned short* hnx      = hring + (size_t)(gs & 7) * HBUF_ELEMS;       // h_gs

    // ---- prefetch A fragments for this wave's (M-half, K-quarter) ----
    s16x8 areg[17];
#pragma unroll
    for (int i = 0; i < 17; ++i) {
      const int s = ks0 + i;
      if (s < 4) { // x part (K 0..63) — only waves 0,1 (q==0)
        const int fk = s * 16 + kh8;
        if (!dec || t == 0) {
          const int tt = dec ? 511 : gs;
          const float* p = xin + (size_t)mrow * 32768 + tt * 64 + fk;
          s16x8 av;
#pragma unroll
          for (int j = 0; j < 8; ++j) ((unsigned short*)&av)[j] = f2bf(p[j]);
          areg[i] = av;
        } else { // x = previous pred, in red (f32); rows mh*32+l31
          s16x8 av;
#pragma unroll
          for (int j = 0; j < 8; ++j)
            ((unsigned short*)&av)[j] = f2bf(red[(mh * 32 + l31) * 65 + fk + j]);
          areg[i] = av;
        }
      } else { // h part (K 64..1087): n-major ring: elem=(s-4)*4096+row*16+kh8
        areg[i] = *(const s16x8*)(hb + (size_t)(s - 4) * 4096 +
                                  (size_t)mrow * 16 + kh8);
      }
    }

    // ---- gates GEMM: M32 x N64 x 17 ksteps (this wave) ----
    f32x16 acc[2] = {};
#pragma unroll
    for (int i = 0; i < 17; ++i) {
      const int s = ks0 + i;
      const s16x8 b0 = *(const s16x8*)(wl + (size_t)(s * 2 + 0) * 512 + lane * 8);
      const s16x8 b1 = *(const s16x8*)(wl + (size_t)(s * 2 + 1) * 512 + lane * 8);
      acc[0] = __builtin_amdgcn_mfma_f32_32x32x16_bf16(areg[i], b0, acc[0], 0, 0, 0);
      acc[1] = __builtin_amdgcn_mfma_f32_32x32x16_bf16(areg[i], b1, acc[1], 0, 0, 0);
    }

    // ---- cross-wave K reduction (waves q==0 write, q>0 add) ----
    if (q == 0) red_write32(red, acc, lane, mh, nullptr);
    __syncthreads();
    if (q != 0) red_add32(red, acc, lane, mh);
    __syncthreads();

    // ---- activation + state update (tid<256, 4 units/thread); write h as
    //      ONE u64 agent atomic per thread (R17-proven write-through) ----
    if (tid < 256) {
      float hn[4];
#pragma unroll
      for (int j = 0; j < 4; ++j) {
        const int u = auu + j;
        const float gi = red[ar * 65 + u]      + biasg[u];
        const float gf = red[ar * 65 + 16 + u] + biasg[16 + u];
        const float gg = red[ar * 65 + 32 + u] + biasg[32 + u];
        const float go = red[ar * 65 + 48 + u] + biasg[48 + u];
        const float c = sigm(gf) * cst[j] + sigm(gi) * tanh_f(gg);
        cst[j] = c;
        hn[j] = sigm(go) * tanh_f(c);
      }
      union { unsigned short u[4]; unsigned long long ull; } pk;
#pragma unroll
      for (int j = 0; j < 4; ++j) pk.u[j] = f2bf(hn[j]);
      const size_t hq = ((size_t)n * 4096 + (size_t)(bm + ar) * 16 + auu) >> 2;
      __hip_atomic_store((unsigned long long*)hnx + hq, pk.ull,
                         __ATOMIC_RELAXED, __HIP_MEMORY_SCOPE_AGENT);
    }
    __syncthreads(); // all h stores drained before tid0 arrives

    // ---- per-m-group barrier (R17 go-line form): arrival fetch_add(1) on
    //      count word (no pollers there); last arriver (old==63) broadcasts
    //      stamp gs+1 to 4 go-lines; waiters PURE-SPIN RMW-poll their
    //      go-line (no s_sleep -- detect lag was >=512cyc/check at DVFS
    //      clocks). Decoder post-poll acquire fence. ----
    if (tid == 0) {
      unsigned int* fl = flags + m * 576 + gs;
      unsigned int old = __hip_atomic_fetch_add(fl, 1u, __ATOMIC_RELAXED,
                                                __HIP_MEMORY_SCOPE_AGENT);
      if (old == 63u) {
        const unsigned int stamp = (unsigned int)gs + 1u;
#pragma unroll
        for (int sb = 0; sb < 4; ++sb)
          __hip_atomic_store(flags + GO_BASE + (m * 4 + sb) * 32, stamp,
                             __ATOMIC_RELAXED, __HIP_MEMORY_SCOPE_AGENT);
      } else {
        unsigned int* go = flags + GO_BASE + (m * 4 + (n >> 4)) * 32;
        for (;;) {
          unsigned int v = __hip_atomic_fetch_add(go, 0u, __ATOMIC_RELAXED,
                                                  __HIP_MEMORY_SCOPE_AGENT);
          if (v > (unsigned int)gs) break;
        }
      }
      if (dec) __builtin_amdgcn_fence(__ATOMIC_ACQUIRE, "agent");
    }
    __syncthreads();

    // ---- decoder: pred = h_new @ W_fc^T + b_fc; kept in red as next x;
    //      n==0 writes out. Wave = (mh, q): M32 x N64 x 16 ksteps. ----
    if (dec && (n == 0 || t < 63)) {
      f32x16 pacc[2] = {};
      const int ps0 = q * 16;
#pragma unroll 4
      for (int i = 0; i < 16; ++i) {
        const int k = (ps0 + i) * 16 + kh8;
        const unsigned short* hp =
            hnx + (size_t)(ps0 + i) * 4096 + (size_t)mrow * 16 + kh8;
        const unsigned short* wp = wfcb + (size_t)l31 * 1024 + k;
        const s16x8 a0 = *(const s16x8*)hp;
        const s16x8 b0 = *(const s16x8*)wp;            // out cols 0..31
        const s16x8 b1 = *(const s16x8*)(wp + 32 * 1024); // out cols 32..63
        pacc[0] = __builtin_amdgcn_mfma_f32_32x32x16_bf16(a0, b0, pacc[0], 0, 0, 0);
        pacc[1] = __builtin_amdgcn_mfma_f32_32x32x16_bf16(a0, b1, pacc[1], 0, 0, 0);
      }
      if (q == 0) red_write32(red, pacc, lane, mh, biasfc);
      __syncthreads();
      if (q != 0) red_add32(red, pacc, lane, mh);
      __syncthreads();
      if (n == 0) {
        const int ob = tid >> 3;          // out row 0..63
        const int oc = (tid & 7) << 3;    // 8 cols per thread
        float* op = out + (size_t)(bm + ob) * 4096 + t * 64 + oc;
#pragma unroll
        for (int jj = 0; jj < 8; jj += 4) {
          f32x4 v = { red[ob * 65 + oc + jj],     red[ob * 65 + oc + jj + 1],
                      red[ob * 65 + oc + jj + 2], red[ob * 65 + oc + jj + 3] };
          *(f32x4*)(op + jj) = v;
        }
      }
      __syncthreads(); // red stable before next step's x reads
    }
  }
}

extern "C" void kernel_launch(void* const* d_in, const int* in_sizes, int n_in,
                              void* d_out, int out_size, void* d_ws, size_t ws_size,
                              hipStream_t stream) {
  (void)in_sizes; (void)n_in; (void)out_size; (void)ws_size;
  const float* xin   = (const float*)d_in[0];
  const float* Wih_e = (const float*)d_in[1];
  const float* Whh_e = (const float*)d_in[2];
  const float* bih_e = (const float*)d_in[3];
  const float* bhh_e = (const float*)d_in[4];
  const float* Wih_d = (const float*)d_in[5];
  const float* Whh_d = (const float*)d_in[6];
  const float* bih_d = (const float*)d_in[7];
  const float* bhh_d = (const float*)d_in[8];
  const float* Wfc   = (const float*)d_in[9];
  const float* bfc   = (const float*)d_in[10];
  float* out = (float*)d_out;

  char* ws = (char*)d_ws;
  unsigned int* flags   = (unsigned int*)(ws + WS_FLAGS);
  unsigned short* hring = (unsigned short*)(ws + WS_HRING);
  unsigned short* wfcb  = (unsigned short*)(ws + WS_WFC);

  hipFuncSetAttribute((const void*)seq2seq_lstm,
                      hipFuncAttributeMaxDynamicSharedMemorySize, LDS_BYTES);

  void* args[] = {
    (void*)&xin, (void*)&Wih_e, (void*)&Whh_e, (void*)&bih_e, (void*)&bhh_e,
    (void*)&Wih_d, (void*)&Whh_d, (void*)&bih_d, (void*)&bhh_d,
    (void*)&Wfc, (void*)&bfc, (void*)&out, (void*)&hring,
    (void*)&wfcb, (void*)&flags
  };
  hipLaunchCooperativeKernel((const void*)seq2seq_lstm, dim3(256), dim3(512),
                             args, LDS_BYTES, stream);
}

// Round 11
// 14227.551 us; speedup vs baseline: 1.0164x; 1.0164x over previous
//
#include <hip/hip_runtime.h>
#include <hip/hip_cooperative_groups.h>
#include <stdint.h>
#include <stddef.h>

namespace cg = cooperative_groups;

// ---------------------------------------------------------------------------
// Seq2Seq LSTM, MI355X persistent cooperative kernel.
// B=256, S=512, F=64, H=1024, T=64.  f32 I/O, bf16 MFMA internals.
//
// R23 -> R24: COMPILE FIX ONLY. s_sleep requires a constant arg; the
// variable backoff (1<<bk) didn't compile. Replaced with a constant-arg
// ladder (if-chain s_sleep(1/2/4/8)). Design identical to R23:
// delete the m-group barrier; dataflow stamps instead.
//   writer: h stores (relaxed agent atomic u64 write-through, R17-proven)
//           -> __syncthreads (vmcnt ack: stores complete at LLC)
//           -> tid0 fire-and-forget stamp[m,n] = gs+1 (relaxed agent).
//   reader WAVE: RMW-polls ONLY its own K-quarter's 13-17 supplier stamps
//           (one lane per slice, wave-parallel, constant-sleep backoff),
//           then loads h. Waves start independently; full-64 coupling gone.
// Skew bound: publishing h_gs requires observing all 64 stamps >= gs =>
// max inter-WG skew 1 step << ring slack 7. Staleness invariants
// unchanged: 8-step acquire fence (encoder), per-step post-wait acquire
// fence (decoder). Workgroup-scope acquire fence after each poll prevents
// compiler hoisting h loads above the wait.
// Stamps: flags words SLOT(m,n) = (m*64 + digitswap4x16(n))*8 (32B stride,
// 8KB total, fits the existing 12288B pad).
//
// 256 WGs = 4 batch-groups (m, 64 rows) x 64 gate-slices (n, 16 hidden
// units -> 64 gate rows i/f/g/o). 512 thr / 8 waves / 2 per SIMD; wave =
// (mh = wave&1, q = wave>>1): gates M32xN64x17ksteps, decoder
// M32xN64x16ksteps. Weights persistent in LDS (139 KB, MFMA-B fragment
// order). h ring n-major: elem = n*4096 + row*16 + (k&15), per-WG 2KB
// private block. c-state in registers (4/thread, tid<256).
// ---------------------------------------------------------------------------

typedef short s16x8 __attribute__((ext_vector_type(8)));
typedef float f32x4 __attribute__((ext_vector_type(4)));
typedef float f32x16 __attribute__((ext_vector_type(16)));

#define LDS_BYTES  156416
#define RED_OFF    139264   // 64x65 f32 reduction buffer
#define BIASG_OFF  155904   // 64 f32 gate bias
#define BIASFC_OFF 156160   // 64 f32 fc bias

// workspace layout (bytes)
#define WS_FLAGS 0          // stamps: 4m x 64n x 32B = 8192 B (< 12288 pad)
#define WS_HRING 12288      // 8 x 524288 B (ring of 256x1024 bf16 buffers)
#define WS_WFC   4206592    // 131072 B (64x1024 bf16)
// total: 4337664 B

#define HBUF_ELEMS 262144   // 256*1024 bf16 elements per ring buffer

// stamp slot word index: 32B stride; 4x16 digit swap spreads contiguous
// slice indices across lines (both writer and readers use this map).
#define SLOT(mm,nn) (((mm) * 64 + ((((nn) & 15) << 2) | ((nn) >> 4))) * 8)

__device__ __forceinline__ void sleep_bk(int bk) {
  if (bk == 0)      __builtin_amdgcn_s_sleep(1);
  else if (bk == 1) __builtin_amdgcn_s_sleep(2);
  else if (bk == 2) __builtin_amdgcn_s_sleep(4);
  else              __builtin_amdgcn_s_sleep(8);
}

__device__ __forceinline__ unsigned short f2bf(float f) {
  union { unsigned int i; float f; } v;
  v.f = f;
  unsigned int i = v.i;
  return (unsigned short)((i + 0x7FFFu + ((i >> 16) & 1u)) >> 16);
}
__device__ __forceinline__ float sigm(float x) { return 1.f / (1.f + __expf(-x)); }
__device__ __forceinline__ float tanh_f(float x) {
  float e = __expf(2.f * x);
  return 1.f - 2.f / (e + 1.f);
}

// Stage this WG's weight slice (f32 global -> bf16 LDS, MFMA-B fragment
// order). 8 waves (f += 8).
__device__ __forceinline__ void load_wg(unsigned short* wl, float* biasg,
    const float* Wih, const float* Whh, const float* bih, const float* bhh,
    int n, int wave, int lane, int tid) {
  const int l31 = lane & 31;
  const int kh8 = (lane >> 5) << 3;
  for (int f = wave; f < 136; f += 8) {
    const int s  = f >> 1;
    const int t2 = f & 1;
    const int col = t2 * 32 + l31;
    const int k0  = s * 16 + kh8;
    const int r   = (col >> 4) * 1024 + n * 16 + (col & 15);
    const float* src = (s < 4) ? (Wih + (size_t)r * 64 + k0)
                               : (Whh + (size_t)r * 1024 + (k0 - 64));
    s16x8 w;
#pragma unroll
    for (int j = 0; j < 8; ++j) ((unsigned short*)&w)[j] = f2bf(src[j]);
    *(s16x8*)(wl + (size_t)f * 512 + lane * 8) = w;
  }
  if (tid < 64) {
    const int r = (tid >> 4) * 1024 + n * 16 + (tid & 15);
    biasg[tid] = bih[r] + bhh[r];
  }
}

// C/D layout (m74/m101-verified): col = lane&31,
// row = (r&3) + 8*(r>>2) + 4*(lane>>5), r in [0,16). mh = M-half (0/1).
__device__ __forceinline__ void red_write32(float* red, const f32x16 (&acc)[2],
                                            int lane, int mh, const float* bias) {
#pragma unroll
  for (int t2 = 0; t2 < 2; ++t2)
#pragma unroll
    for (int r = 0; r < 16; ++r) {
      const int row = mh * 32 + (r & 3) + ((r >> 2) << 3) + ((lane >> 5) << 2);
      const int col = t2 * 32 + (lane & 31);
      float v = acc[t2][r];
      if (bias) v += bias[col];
      red[row * 65 + col] = v;
    }
}
__device__ __forceinline__ void red_add32(float* red, const f32x16 (&acc)[2],
                                          int lane, int mh) {
#pragma unroll
  for (int t2 = 0; t2 < 2; ++t2)
#pragma unroll
    for (int r = 0; r < 16; ++r) {
      const int row = mh * 32 + (r & 3) + ((r >> 2) << 3) + ((lane >> 5) << 2);
      const int col = t2 * 32 + (lane & 31);
      atomicAdd(red + row * 65 + col, acc[t2][r]);
    }
}

__global__ void __launch_bounds__(512, 1) seq2seq_lstm(
    const float* __restrict__ xin,
    const float* __restrict__ Wih_e,
    const float* __restrict__ Whh_e,
    const float* __restrict__ bih_e,
    const float* __restrict__ bhh_e,
    const float* __restrict__ Wih_d,
    const float* __restrict__ Whh_d,
    const float* __restrict__ bih_d,
    const float* __restrict__ bhh_d,
    const float* __restrict__ Wfc,
    const float* __restrict__ bfc,
    float* __restrict__ out,
    unsigned short* __restrict__ hring,
    unsigned short* __restrict__ wfcb,
    unsigned int* __restrict__ flags) {
  extern __shared__ char smem[];
  unsigned short* wl = (unsigned short*)smem;
  float* red    = (float*)(smem + RED_OFF);
  float* biasg  = (float*)(smem + BIASG_OFF);
  float* biasfc = (float*)(smem + BIASFC_OFF);

  cg::grid_group grid = cg::this_grid();

  const int tid  = threadIdx.x;
  const int wave = tid >> 6;   // 0..7
  const int lane = tid & 63;
  const int wg   = blockIdx.x;
  const int m    = wg & 3;     // batch-group (XCD-locality swizzle)
  const int n    = wg >> 2;    // gate-slice
  const int bm   = m << 6;
  const int l31  = lane & 31;
  const int kh8  = (lane >> 5) << 3;
  const int mh   = wave & 1;   // M-half (rows mh*32..mh*32+31)
  const int q    = wave >> 1;  // K-quarter
  const int ks0  = q * 17;     // gates: this wave's k-step base (of 68)
  const int mrow = bm + mh * 32 + l31; // this lane's A row
  // activation mapping (tid < 256): row ar = tid>>2, units auu..auu+3
  const int ar   = tid >> 2;
  const int auu  = (tid & 3) << 2;

  load_wg(wl, biasg, Wih_e, Whh_e, bih_e, bhh_e, n, wave, lane, tid);

  // In-kernel init: zero ring buffer 7 (h_{-1}, this WG's n-major slice);
  // zero own stamp slot; convert W_fc slice. grid.sync publishes.
  {
    if (tid < 256) {
      unsigned short* hinit = hring + (size_t)7 * HBUF_ELEMS;
      const size_t hq = ((size_t)n * 4096 + (size_t)(bm + ar) * 16 + auu) >> 2;
      __hip_atomic_store((unsigned long long*)hinit + hq, 0ull,
                         __ATOMIC_RELAXED, __HIP_MEMORY_SCOPE_AGENT);
      wfcb[wg * 256 + tid] = f2bf(Wfc[wg * 256 + tid]);
    }
    if (tid == 0)
      __hip_atomic_store(flags + SLOT(m, n), 0u,
                         __ATOMIC_RELAXED, __HIP_MEMORY_SCOPE_AGENT);
  }
  __syncthreads();
  grid.sync(); // one-time full-coherence publish of init state

  float cst[4] = {0.f, 0.f, 0.f, 0.f};

  for (int gs = 0; gs < 576; ++gs) {
    const bool dec = (gs >= 512);
    const int t = gs - 512;

    // ---- amortized acquire fence: every 8 steps, before any h read ----
    if ((gs & 7) == 0 && gs != 0) {
      if (tid == 0) __builtin_amdgcn_fence(__ATOMIC_ACQUIRE, "agent");
      __syncthreads();
    }

    if (gs == 512) {
      __syncthreads();
      load_wg(wl, biasg, Wih_d, Whh_d, bih_d, bhh_d, n, wave, lane, tid);
      if (tid < 64) biasfc[tid] = bfc[tid];
      __syncthreads();
    }
    const unsigned short* hb = hring + (size_t)((gs + 7) & 7) * HBUF_ELEMS; // h_{gs-1}
    unsigned short* hnx      = hring + (size_t)(gs & 7) * HBUF_ELEMS;       // h_gs

    // ---- per-wave dataflow wait: this wave's K-quarter needs h_{gs-1}
    //      slices ks0-4..ks0+12 (s>=4 only). Lane i<17 polls slice
    //      ks0+i-4 via fetch_add(0) (LLC-fresh); constant-sleep backoff ----
    {
      const int s = ks0 + lane;
      const bool need = (lane < 17) && (s >= 4);
      unsigned int* sp = flags + (need ? SLOT(m, s - 4) : SLOT(m, 0));
      const unsigned int thr = (unsigned int)gs;
      int bk = 0;
      for (;;) {
        unsigned int v = need ? __hip_atomic_fetch_add(sp, 0u, __ATOMIC_RELAXED,
                                                       __HIP_MEMORY_SCOPE_AGENT)
                              : thr;
        if (__all((int)(v >= thr))) break;
        sleep_bk(bk);
        if (bk < 3) ++bk;
      }
      __builtin_amdgcn_fence(__ATOMIC_ACQUIRE, "workgroup"); // no load hoisting
    }

    // ---- prefetch A fragments for this wave's (M-half, K-quarter) ----
    s16x8 areg[17];
#pragma unroll
    for (int i = 0; i < 17; ++i) {
      const int s = ks0 + i;
      if (s < 4) { // x part (K 0..63) — only waves 0,1 (q==0)
        const int fk = s * 16 + kh8;
        if (!dec || t == 0) {
          const int tt = dec ? 511 : gs;
          const float* p = xin + (size_t)mrow * 32768 + tt * 64 + fk;
          s16x8 av;
#pragma unroll
          for (int j = 0; j < 8; ++j) ((unsigned short*)&av)[j] = f2bf(p[j]);
          areg[i] = av;
        } else { // x = previous pred, in red (f32); rows mh*32+l31
          s16x8 av;
#pragma unroll
          for (int j = 0; j < 8; ++j)
            ((unsigned short*)&av)[j] = f2bf(red[(mh * 32 + l31) * 65 + fk + j]);
          areg[i] = av;
        }
      } else { // h part (K 64..1087): n-major ring: elem=(s-4)*4096+row*16+kh8
        areg[i] = *(const s16x8*)(hb + (size_t)(s - 4) * 4096 +
                                  (size_t)mrow * 16 + kh8);
      }
    }

    // ---- gates GEMM: M32 x N64 x 17 ksteps (this wave) ----
    f32x16 acc[2] = {};
#pragma unroll
    for (int i = 0; i < 17; ++i) {
      const int s = ks0 + i;
      const s16x8 b0 = *(const s16x8*)(wl + (size_t)(s * 2 + 0) * 512 + lane * 8);
      const s16x8 b1 = *(const s16x8*)(wl + (size_t)(s * 2 + 1) * 512 + lane * 8);
      acc[0] = __builtin_amdgcn_mfma_f32_32x32x16_bf16(areg[i], b0, acc[0], 0, 0, 0);
      acc[1] = __builtin_amdgcn_mfma_f32_32x32x16_bf16(areg[i], b1, acc[1], 0, 0, 0);
    }

    // ---- cross-wave K reduction (waves q==0 write, q>0 add) ----
    if (q == 0) red_write32(red, acc, lane, mh, nullptr);
    __syncthreads();
    if (q != 0) red_add32(red, acc, lane, mh);
    __syncthreads();

    // ---- activation + state update (tid<256, 4 units/thread); write h as
    //      ONE u64 agent atomic per thread (R17-proven write-through) ----
    if (tid < 256) {
      float hn[4];
#pragma unroll
      for (int j = 0; j < 4; ++j) {
        const int u = auu + j;
        const float gi = red[ar * 65 + u]      + biasg[u];
        const float gf = red[ar * 65 + 16 + u] + biasg[16 + u];
        const float gg = red[ar * 65 + 32 + u] + biasg[32 + u];
        const float go = red[ar * 65 + 48 + u] + biasg[48 + u];
        const float c = sigm(gf) * cst[j] + sigm(gi) * tanh_f(gg);
        cst[j] = c;
        hn[j] = sigm(go) * tanh_f(c);
      }
      union { unsigned short u[4]; unsigned long long ull; } pk;
#pragma unroll
      for (int j = 0; j < 4; ++j) pk.u[j] = f2bf(hn[j]);
      const size_t hq = ((size_t)n * 4096 + (size_t)(bm + ar) * 16 + auu) >> 2;
      __hip_atomic_store((unsigned long long*)hnx + hq, pk.ull,
                         __ATOMIC_RELAXED, __HIP_MEMORY_SCOPE_AGENT);
    }
    __syncthreads(); // vmcnt drain: all h stores COMPLETE (ack'd) at LLC

    // ---- publish: fire-and-forget stamp (no wait, no barrier) ----
    if (tid == 0)
      __hip_atomic_store(flags + SLOT(m, n), (unsigned int)gs + 1u,
                         __ATOMIC_RELAXED, __HIP_MEMORY_SCOPE_AGENT);

    // ---- decoder: pred = h_new @ W_fc^T + b_fc; kept in red as next x;
    //      n==0 writes out. Per-wave wait for h_gs slices, then acquire
    //      fence (R6-proven), then M32 x N64 x 16 ksteps. ----
    if (dec && (n == 0 || t < 63)) {
      {
        const bool need = (lane < 16);
        const int sl = q * 16 + (lane & 15);
        unsigned int* sp = flags + SLOT(m, sl);
        const unsigned int thr = (unsigned int)gs + 1u;
        int bk = 0;
        for (;;) {
          unsigned int v = need ? __hip_atomic_fetch_add(sp, 0u, __ATOMIC_RELAXED,
                                                         __HIP_MEMORY_SCOPE_AGENT)
                                : thr;
          if (__all((int)(v >= thr))) break;
          sleep_bk(bk);
          if (bk < 3) ++bk;
        }
      }
      __syncthreads();
      if (tid == 0) __builtin_amdgcn_fence(__ATOMIC_ACQUIRE, "agent");
      __syncthreads();

      f32x16 pacc[2] = {};
      const int ps0 = q * 16;
#pragma unroll 4
      for (int i = 0; i < 16; ++i) {
        const int k = (ps0 + i) * 16 + kh8;
        const unsigned short* hp =
            hnx + (size_t)(ps0 + i) * 4096 + (size_t)mrow * 16 + kh8;
        const unsigned short* wp = wfcb + (size_t)l31 * 1024 + k;
        const s16x8 a0 = *(const s16x8*)hp;
        const s16x8 b0 = *(const s16x8*)wp;            // out cols 0..31
        const s16x8 b1 = *(const s16x8*)(wp + 32 * 1024); // out cols 32..63
        pacc[0] = __builtin_amdgcn_mfma_f32_32x32x16_bf16(a0, b0, pacc[0], 0, 0, 0);
        pacc[1] = __builtin_amdgcn_mfma_f32_32x32x16_bf16(a0, b1, pacc[1], 0, 0, 0);
      }
      if (q == 0) red_write32(red, pacc, lane, mh, biasfc);
      __syncthreads();
      if (q != 0) red_add32(red, pacc, lane, mh);
      __syncthreads();
      if (n == 0) {
        const int ob = tid >> 3;          // out row 0..63
        const int oc = (tid & 7) << 3;    // 8 cols per thread
        float* op = out + (size_t)(bm + ob) * 4096 + t * 64 + oc;
#pragma unroll
        for (int jj = 0; jj < 8; jj += 4) {
          f32x4 v = { red[ob * 65 + oc + jj],     red[ob * 65 + oc + jj + 1],
                      red[ob * 65 + oc + jj + 2], red[ob * 65 + oc + jj + 3] };
          *(f32x4*)(op + jj) = v;
        }
      }
      __syncthreads(); // red stable before next step's x reads
    }
  }
}

extern "C" void kernel_launch(void* const* d_in, const int* in_sizes, int n_in,
                              void* d_out, int out_size, void* d_ws, size_t ws_size,
                              hipStream_t stream) {
  (void)in_sizes; (void)n_in; (void)out_size; (void)ws_size;
  const float* xin   = (const float*)d_in[0];
  const float* Wih_e = (const float*)d_in[1];
  const float* Whh_e = (const float*)d_in[2];
  const float* bih_e = (const float*)d_in[3];
  const float* bhh_e = (const float*)d_in[4];
  const float* Wih_d = (const float*)d_in[5];
  const float* Whh_d = (const float*)d_in[6];
  const float* bih_d = (const float*)d_in[7];
  const float* bhh_d = (const float*)d_in[8];
  const float* Wfc   = (const float*)d_in[9];
  const float* bfc   = (const float*)d_in[10];
  float* out = (float*)d_out;

  char* ws = (char*)d_ws;
  unsigned int* flags   = (unsigned int*)(ws + WS_FLAGS);
  unsigned short* hring = (unsigned short*)(ws + WS_HRING);
  unsigned short* wfcb  = (unsigned short*)(ws + WS_WFC);

  hipFuncSetAttribute((const void*)seq2seq_lstm,
                      hipFuncAttributeMaxDynamicSharedMemorySize, LDS_BYTES);

  void* args[] = {
    (void*)&xin, (void*)&Wih_e, (void*)&Whh_e, (void*)&bih_e, (void*)&bhh_e,
    (void*)&Wih_d, (void*)&Whh_d, (void*)&bih_d, (void*)&bhh_d,
    (void*)&Wfc, (void*)&bfc, (void*)&out, (void*)&hring,
    (void*)&wfcb, (void*)&flags
  };
  hipLaunchCooperativeKernel((const void*)seq2seq_lstm, dim3(256), dim3(512),
                             args, LDS_BYTES, stream);
}

// Round 12
// 14177.737 us; speedup vs baseline: 1.0200x; 1.0035x over previous
//
#include <hip/hip_runtime.h>
#include <hip/hip_cooperative_groups.h>
#include <stdint.h>
#include <stddef.h>

namespace cg = cooperative_groups;

// ---------------------------------------------------------------------------
// Seq2Seq LSTM, MI355X persistent cooperative kernel.
// B=256, S=512, F=64, H=1024, T=64.  f32 I/O, bf16 MFMA internals.
//
// R24 -> R25: DVFS attack. Clock back-computed from R24 counters:
// 40M MFMA x 8cyc / 1024 SIMDs = 312K busy-cyc; MfmaUtil 4.08% => 7.7M
// total cyc over 14.2ms => ~540 MHz sustained (vs 2400 max). A ~96%-parked
// kernel pins DVFS at floor; every LLC RTT / drain / compute cycle is 4.4x
// slower. Chain model at 2.4GHz (~5.5us/step) x 4.45 = 24.5us/step =
// measured 24.7. Explains why 5 sync-topology changes were all flat.
// Fix: replace s_sleep backoff in both poll loops with a ~256-cycle
// dependent VALU busy-chain (asm volatile, not DCE-able). All 8 waves stay
// hot during the dominant wait phase -> activity monitors see busy SIMDs
// -> SCLK ramps. Also rate-limits stamp polls (~1 burst/300cyc). Protocol
// byte-identical to R24 (dataflow stamps, no barrier).
//
// 256 WGs = 4 batch-groups (m, 64 rows) x 64 gate-slices (n, 16 hidden
// units -> 64 gate rows i/f/g/o). 512 thr / 8 waves / 2 per SIMD; wave =
// (mh = wave&1, q = wave>>1): gates M32xN64x17ksteps, decoder
// M32xN64x16ksteps. Weights persistent in LDS (139 KB, MFMA-B fragment
// order). h ring n-major: elem = n*4096 + row*16 + (k&15), per-WG 2KB
// private block. c-state in registers (4/thread, tid<256).
// ---------------------------------------------------------------------------

typedef short s16x8 __attribute__((ext_vector_type(8)));
typedef float f32x4 __attribute__((ext_vector_type(4)));
typedef float f32x16 __attribute__((ext_vector_type(16)));

#define LDS_BYTES  156416
#define RED_OFF    139264   // 64x65 f32 reduction buffer
#define BIASG_OFF  155904   // 64 f32 gate bias
#define BIASFC_OFF 156160   // 64 f32 fc bias

// workspace layout (bytes)
#define WS_FLAGS 0          // stamps: 4m x 64n x 32B = 8192 B (< 12288 pad)
#define WS_HRING 12288      // 8 x 524288 B (ring of 256x1024 bf16 buffers)
#define WS_WFC   4206592    // 131072 B (64x1024 bf16)
// total: 4337664 B

#define HBUF_ELEMS 262144   // 256*1024 bf16 elements per ring buffer

// stamp slot word index: 32B stride; 4x16 digit swap spreads contiguous
// slice indices across lines (both writer and readers use this map).
#define SLOT(mm,nn) (((mm) * 64 + ((((nn) & 15) << 2) | ((nn) >> 4))) * 8)

// ~256-cycle dependent VALU chain: keeps the SIMD busy between polls so
// DVFS activity monitors see work (clock ramp), and rate-limits polls.
__device__ __forceinline__ void spin_filler() {
  float x = 1.0f;
#pragma unroll
  for (int i = 0; i < 64; ++i)
    asm volatile("v_add_f32 %0, %0, %0" : "+v"(x));
}

__device__ __forceinline__ unsigned short f2bf(float f) {
  union { unsigned int i; float f; } v;
  v.f = f;
  unsigned int i = v.i;
  return (unsigned short)((i + 0x7FFFu + ((i >> 16) & 1u)) >> 16);
}
__device__ __forceinline__ float sigm(float x) { return 1.f / (1.f + __expf(-x)); }
__device__ __forceinline__ float tanh_f(float x) {
  float e = __expf(2.f * x);
  return 1.f - 2.f / (e + 1.f);
}

// Stage this WG's weight slice (f32 global -> bf16 LDS, MFMA-B fragment
// order). 8 waves (f += 8).
__device__ __forceinline__ void load_wg(unsigned short* wl, float* biasg,
    const float* Wih, const float* Whh, const float* bih, const float* bhh,
    int n, int wave, int lane, int tid) {
  const int l31 = lane & 31;
  const int kh8 = (lane >> 5) << 3;
  for (int f = wave; f < 136; f += 8) {
    const int s  = f >> 1;
    const int t2 = f & 1;
    const int col = t2 * 32 + l31;
    const int k0  = s * 16 + kh8;
    const int r   = (col >> 4) * 1024 + n * 16 + (col & 15);
    const float* src = (s < 4) ? (Wih + (size_t)r * 64 + k0)
                               : (Whh + (size_t)r * 1024 + (k0 - 64));
    s16x8 w;
#pragma unroll
    for (int j = 0; j < 8; ++j) ((unsigned short*)&w)[j] = f2bf(src[j]);
    *(s16x8*)(wl + (size_t)f * 512 + lane * 8) = w;
  }
  if (tid < 64) {
    const int r = (tid >> 4) * 1024 + n * 16 + (tid & 15);
    biasg[tid] = bih[r] + bhh[r];
  }
}

// C/D layout (m74/m101-verified): col = lane&31,
// row = (r&3) + 8*(r>>2) + 4*(lane>>5), r in [0,16). mh = M-half (0/1).
__device__ __forceinline__ void red_write32(float* red, const f32x16 (&acc)[2],
                                            int lane, int mh, const float* bias) {
#pragma unroll
  for (int t2 = 0; t2 < 2; ++t2)
#pragma unroll
    for (int r = 0; r < 16; ++r) {
      const int row = mh * 32 + (r & 3) + ((r >> 2) << 3) + ((lane >> 5) << 2);
      const int col = t2 * 32 + (lane & 31);
      float v = acc[t2][r];
      if (bias) v += bias[col];
      red[row * 65 + col] = v;
    }
}
__device__ __forceinline__ void red_add32(float* red, const f32x16 (&acc)[2],
                                          int lane, int mh) {
#pragma unroll
  for (int t2 = 0; t2 < 2; ++t2)
#pragma unroll
    for (int r = 0; r < 16; ++r) {
      const int row = mh * 32 + (r & 3) + ((r >> 2) << 3) + ((lane >> 5) << 2);
      const int col = t2 * 32 + (lane & 31);
      atomicAdd(red + row * 65 + col, acc[t2][r]);
    }
}

__global__ void __launch_bounds__(512, 1) seq2seq_lstm(
    const float* __restrict__ xin,
    const float* __restrict__ Wih_e,
    const float* __restrict__ Whh_e,
    const float* __restrict__ bih_e,
    const float* __restrict__ bhh_e,
    const float* __restrict__ Wih_d,
    const float* __restrict__ Whh_d,
    const float* __restrict__ bih_d,
    const float* __restrict__ bhh_d,
    const float* __restrict__ Wfc,
    const float* __restrict__ bfc,
    float* __restrict__ out,
    unsigned short* __restrict__ hring,
    unsigned short* __restrict__ wfcb,
    unsigned int* __restrict__ flags) {
  extern __shared__ char smem[];
  unsigned short* wl = (unsigned short*)smem;
  float* red    = (float*)(smem + RED_OFF);
  float* biasg  = (float*)(smem + BIASG_OFF);
  float* biasfc = (float*)(smem + BIASFC_OFF);

  cg::grid_group grid = cg::this_grid();

  const int tid  = threadIdx.x;
  const int wave = tid >> 6;   // 0..7
  const int lane = tid & 63;
  const int wg   = blockIdx.x;
  const int m    = wg & 3;     // batch-group (XCD-locality swizzle)
  const int n    = wg >> 2;    // gate-slice
  const int bm   = m << 6;
  const int l31  = lane & 31;
  const int kh8  = (lane >> 5) << 3;
  const int mh   = wave & 1;   // M-half (rows mh*32..mh*32+31)
  const int q    = wave >> 1;  // K-quarter
  const int ks0  = q * 17;     // gates: this wave's k-step base (of 68)
  const int mrow = bm + mh * 32 + l31; // this lane's A row
  // activation mapping (tid < 256): row ar = tid>>2, units auu..auu+3
  const int ar   = tid >> 2;
  const int auu  = (tid & 3) << 2;

  load_wg(wl, biasg, Wih_e, Whh_e, bih_e, bhh_e, n, wave, lane, tid);

  // In-kernel init: zero ring buffer 7 (h_{-1}, this WG's n-major slice);
  // zero own stamp slot; convert W_fc slice. grid.sync publishes.
  {
    if (tid < 256) {
      unsigned short* hinit = hring + (size_t)7 * HBUF_ELEMS;
      const size_t hq = ((size_t)n * 4096 + (size_t)(bm + ar) * 16 + auu) >> 2;
      __hip_atomic_store((unsigned long long*)hinit + hq, 0ull,
                         __ATOMIC_RELAXED, __HIP_MEMORY_SCOPE_AGENT);
      wfcb[wg * 256 + tid] = f2bf(Wfc[wg * 256 + tid]);
    }
    if (tid == 0)
      __hip_atomic_store(flags + SLOT(m, n), 0u,
                         __ATOMIC_RELAXED, __HIP_MEMORY_SCOPE_AGENT);
  }
  __syncthreads();
  grid.sync(); // one-time full-coherence publish of init state

  float cst[4] = {0.f, 0.f, 0.f, 0.f};

  for (int gs = 0; gs < 576; ++gs) {
    const bool dec = (gs >= 512);
    const int t = gs - 512;

    // ---- amortized acquire fence: every 8 steps, before any h read ----
    if ((gs & 7) == 0 && gs != 0) {
      if (tid == 0) __builtin_amdgcn_fence(__ATOMIC_ACQUIRE, "agent");
      __syncthreads();
    }

    if (gs == 512) {
      __syncthreads();
      load_wg(wl, biasg, Wih_d, Whh_d, bih_d, bhh_d, n, wave, lane, tid);
      if (tid < 64) biasfc[tid] = bfc[tid];
      __syncthreads();
    }
    const unsigned short* hb = hring + (size_t)((gs + 7) & 7) * HBUF_ELEMS; // h_{gs-1}
    unsigned short* hnx      = hring + (size_t)(gs & 7) * HBUF_ELEMS;       // h_gs

    // ---- per-wave dataflow wait: this wave's K-quarter needs h_{gs-1}
    //      slices ks0-4..ks0+12 (s>=4 only). Lane i<17 polls slice
    //      ks0+i-4 via fetch_add(0) (LLC-fresh); VALU busy-spin filler
    //      between polls keeps SIMDs hot (DVFS) and rate-limits polls. ----
    {
      const int s = ks0 + lane;
      const bool need = (lane < 17) && (s >= 4);
      unsigned int* sp = flags + (need ? SLOT(m, s - 4) : SLOT(m, 0));
      const unsigned int thr = (unsigned int)gs;
      for (;;) {
        unsigned int v = need ? __hip_atomic_fetch_add(sp, 0u, __ATOMIC_RELAXED,
                                                       __HIP_MEMORY_SCOPE_AGENT)
                              : thr;
        if (__all((int)(v >= thr))) break;
        spin_filler();
      }
      __builtin_amdgcn_fence(__ATOMIC_ACQUIRE, "workgroup"); // no load hoisting
    }

    // ---- prefetch A fragments for this wave's (M-half, K-quarter) ----
    s16x8 areg[17];
#pragma unroll
    for (int i = 0; i < 17; ++i) {
      const int s = ks0 + i;
      if (s < 4) { // x part (K 0..63) — only waves 0,1 (q==0)
        const int fk = s * 16 + kh8;
        if (!dec || t == 0) {
          const int tt = dec ? 511 : gs;
          const float* p = xin + (size_t)mrow * 32768 + tt * 64 + fk;
          s16x8 av;
#pragma unroll
          for (int j = 0; j < 8; ++j) ((unsigned short*)&av)[j] = f2bf(p[j]);
          areg[i] = av;
        } else { // x = previous pred, in red (f32); rows mh*32+l31
          s16x8 av;
#pragma unroll
          for (int j = 0; j < 8; ++j)
            ((unsigned short*)&av)[j] = f2bf(red[(mh * 32 + l31) * 65 + fk + j]);
          areg[i] = av;
        }
      } else { // h part (K 64..1087): n-major ring: elem=(s-4)*4096+row*16+kh8
        areg[i] = *(const s16x8*)(hb + (size_t)(s - 4) * 4096 +
                                  (size_t)mrow * 16 + kh8);
      }
    }

    // ---- gates GEMM: M32 x N64 x 17 ksteps (this wave) ----
    f32x16 acc[2] = {};
#pragma unroll
    for (int i = 0; i < 17; ++i) {
      const int s = ks0 + i;
      const s16x8 b0 = *(const s16x8*)(wl + (size_t)(s * 2 + 0) * 512 + lane * 8);
      const s16x8 b1 = *(const s16x8*)(wl + (size_t)(s * 2 + 1) * 512 + lane * 8);
      acc[0] = __builtin_amdgcn_mfma_f32_32x32x16_bf16(areg[i], b0, acc[0], 0, 0, 0);
      acc[1] = __builtin_amdgcn_mfma_f32_32x32x16_bf16(areg[i], b1, acc[1], 0, 0, 0);
    }

    // ---- cross-wave K reduction (waves q==0 write, q>0 add) ----
    if (q == 0) red_write32(red, acc, lane, mh, nullptr);
    __syncthreads();
    if (q != 0) red_add32(red, acc, lane, mh);
    __syncthreads();

    // ---- activation + state update (tid<256, 4 units/thread); write h as
    //      ONE u64 agent atomic per thread (R17-proven write-through) ----
    if (tid < 256) {
      float hn[4];
#pragma unroll
      for (int j = 0; j < 4; ++j) {
        const int u = auu + j;
        const float gi = red[ar * 65 + u]      + biasg[u];
        const float gf = red[ar * 65 + 16 + u] + biasg[16 + u];
        const float gg = red[ar * 65 + 32 + u] + biasg[32 + u];
        const float go = red[ar * 65 + 48 + u] + biasg[48 + u];
        const float c = sigm(gf) * cst[j] + sigm(gi) * tanh_f(gg);
        cst[j] = c;
        hn[j] = sigm(go) * tanh_f(c);
      }
      union { unsigned short u[4]; unsigned long long ull; } pk;
#pragma unroll
      for (int j = 0; j < 4; ++j) pk.u[j] = f2bf(hn[j]);
      const size_t hq = ((size_t)n * 4096 + (size_t)(bm + ar) * 16 + auu) >> 2;
      __hip_atomic_store((unsigned long long*)hnx + hq, pk.ull,
                         __ATOMIC_RELAXED, __HIP_MEMORY_SCOPE_AGENT);
    }
    __syncthreads(); // vmcnt drain: all h stores COMPLETE (ack'd) at LLC

    // ---- publish: fire-and-forget stamp (no wait, no barrier) ----
    if (tid == 0)
      __hip_atomic_store(flags + SLOT(m, n), (unsigned int)gs + 1u,
                         __ATOMIC_RELAXED, __HIP_MEMORY_SCOPE_AGENT);

    // ---- decoder: pred = h_new @ W_fc^T + b_fc; kept in red as next x;
    //      n==0 writes out. Per-wave wait for h_gs slices, then acquire
    //      fence (R6-proven), then M32 x N64 x 16 ksteps. ----
    if (dec && (n == 0 || t < 63)) {
      {
        const bool need = (lane < 16);
        const int sl = q * 16 + (lane & 15);
        unsigned int* sp = flags + SLOT(m, sl);
        const unsigned int thr = (unsigned int)gs + 1u;
        for (;;) {
          unsigned int v = need ? __hip_atomic_fetch_add(sp, 0u, __ATOMIC_RELAXED,
                                                         __HIP_MEMORY_SCOPE_AGENT)
                                : thr;
          if (__all((int)(v >= thr))) break;
          spin_filler();
        }
      }
      __syncthreads();
      if (tid == 0) __builtin_amdgcn_fence(__ATOMIC_ACQUIRE, "agent");
      __syncthreads();

      f32x16 pacc[2] = {};
      const int ps0 = q * 16;
#pragma unroll 4
      for (int i = 0; i < 16; ++i) {
        const int k = (ps0 + i) * 16 + kh8;
        const unsigned short* hp =
            hnx + (size_t)(ps0 + i) * 4096 + (size_t)mrow * 16 + kh8;
        const unsigned short* wp = wfcb + (size_t)l31 * 1024 + k;
        const s16x8 a0 = *(const s16x8*)hp;
        const s16x8 b0 = *(const s16x8*)wp;            // out cols 0..31
        const s16x8 b1 = *(const s16x8*)(wp + 32 * 1024); // out cols 32..63
        pacc[0] = __builtin_amdgcn_mfma_f32_32x32x16_bf16(a0, b0, pacc[0], 0, 0, 0);
        pacc[1] = __builtin_amdgcn_mfma_f32_32x32x16_bf16(a0, b1, pacc[1], 0, 0, 0);
      }
      if (q == 0) red_write32(red, pacc, lane, mh, biasfc);
      __syncthreads();
      if (q != 0) red_add32(red, pacc, lane, mh);
      __syncthreads();
      if (n == 0) {
        const int ob = tid >> 3;          // out row 0..63
        const int oc = (tid & 7) << 3;    // 8 cols per thread
        float* op = out + (size_t)(bm + ob) * 4096 + t * 64 + oc;
#pragma unroll
        for (int jj = 0; jj < 8; jj += 4) {
          f32x4 v = { red[ob * 65 + oc + jj],     red[ob * 65 + oc + jj + 1],
                      red[ob * 65 + oc + jj + 2], red[ob * 65 + oc + jj + 3] };
          *(f32x4*)(op + jj) = v;
        }
      }
      __syncthreads(); // red stable before next step's x reads
    }
  }
}

extern "C" void kernel_launch(void* const* d_in, const int* in_sizes, int n_in,
                              void* d_out, int out_size, void* d_ws, size_t ws_size,
                              hipStream_t stream) {
  (void)in_sizes; (void)n_in; (void)out_size; (void)ws_size;
  const float* xin   = (const float*)d_in[0];
  const float* Wih_e = (const float*)d_in[1];
  const float* Whh_e = (const float*)d_in[2];
  const float* bih_e = (const float*)d_in[3];
  const float* bhh_e = (const float*)d_in[4];
  const float* Wih_d = (const float*)d_in[5];
  const float* Whh_d = (const float*)d_in[6];
  const float* bih_d = (const float*)d_in[7];
  const float* bhh_d = (const float*)d_in[8];
  const float* Wfc   = (const float*)d_in[9];
  const float* bfc   = (const float*)d_in[10];
  float* out = (float*)d_out;

  char* ws = (char*)d_ws;
  unsigned int* flags   = (unsigned int*)(ws + WS_FLAGS);
  unsigned short* hring = (unsigned short*)(ws + WS_HRING);
  unsigned short* wfcb  = (unsigned short*)(ws + WS_WFC);

  hipFuncSetAttribute((const void*)seq2seq_lstm,
                      hipFuncAttributeMaxDynamicSharedMemorySize, LDS_BYTES);

  void* args[] = {
    (void*)&xin, (void*)&Wih_e, (void*)&Whh_e, (void*)&bih_e, (void*)&bhh_e,
    (void*)&Wih_d, (void*)&Whh_d, (void*)&bih_d, (void*)&bhh_d,
    (void*)&Wfc, (void*)&bfc, (void*)&out, (void*)&hring,
    (void*)&wfcb, (void*)&flags
  };
  hipLaunchCooperativeKernel((const void*)seq2seq_lstm, dim3(256), dim3(512),
                             args, LDS_BYTES, stream);
}